// Round 1
// baseline (459.447 us; speedup 1.0000x reference)
//
#include <hip/hip_runtime.h>

// FutureTrajDecoder: 3-layer GRU rollout, B=16384, ES=HS=64, T=128, NOUT=2.
// R14: barrier-synced systolic pipeline, replacing R8/R13's flag+spin-poll
// handshake. Diagnosis of R13 (440us): per-t budget 8250 cyc vs ~3500 cyc
// compute floor (2300 of which is the intrinsic transcendental floor:
// 288 trans-instr/SIMD/t at quarter rate). The excess was handshake latency
// under a poll-saturated LDS pipe (65% busy => ~3x queue-inflated latency;
// ~2750 cyc/cell for the serial h2->L0->L1->L2 chain).
// New structure:
//  - 4 batch tiles of 16 rows; diagonal schedule: stage s: L0 does slot s,
//    L1 slot s-1, L2 slot s-2; __syncthreads() between stages (4/t).
//  - all 12 waves active every stage (SIMD g = layers 0..2 of colgroup g):
//    trans work evenly spread (576 cyc/SIMD/stage = floor), reads/MFMAs of
//    one wave hide under SIMD-mates' trans.
//  - no flags, no atomics, no polls: idle = s_barrier (zero LDS traffic).
//  - parity double-buffer kept (h_l(t) in parity t&1); every producer ->
//    consumer pair separated by >=1 barrier; same-parity overwrite is 8
//    stages after the last reader.
// Math/unchanged: emb fold into L0, gate scales folded into weights, biases
// in MFMA C-init, weights = A operand, fp32 carry in VGPRs, MFMA 16x16x32
// f16 fp32-accum, chained x-MFMAs, out-proj from L0's x-frags (= h2(t-1)),
// wave g serves out tile g.

#define ESZ   64
#define HSZ   64
#define TLEN  128
#define NOUTC 2
#define LDW   72              // fp16 row stride (144 B)
#define TB16  (16*LDW)        // one 16-row activation tile buffer
#define L2E   1.44269504f

typedef _Float16 half8 __attribute__((ext_vector_type(8)));
typedef _Float16 half4 __attribute__((ext_vector_type(4)));
typedef float    floatx4 __attribute__((ext_vector_type(4)));
typedef float    floatx2 __attribute__((ext_vector_type(2)));

#define MFMA(a, b, c) __builtin_amdgcn_mfma_f32_16x16x32_f16((a), (b), (c), 0, 0, 0)

__global__ __launch_bounds__(768, 3) void gru_pipe(
    const float* __restrict__ enc,     // (B, 64)
    const float* __restrict__ emb_w,   // (64, 64)
    const float* __restrict__ emb_b,   // (64,)
    const float* __restrict__ w_ih,    // (3, 192, 64)
    const float* __restrict__ w_hh,    // (3, 192, 64)
    const float* __restrict__ b_ih,    // (3, 192)
    const float* __restrict__ b_hh,    // (3, 192)
    const float* __restrict__ out_w,   // (2, 64)
    const float* __restrict__ out_b,   // (2,)
    float* __restrict__ out)           // (B, 128, 2)
{
    __shared__ _Float16 s_hl[3 * 4 * 2 * TB16]; // h_l fp16 [layer][tile][parity]
    __shared__ float    s_btmp[3 * 64];          // folded emb bias (fp32)

    const int tid  = threadIdx.x;
    const int wave = tid >> 6, lane = tid & 63;
    const int l = wave >> 2, g = wave & 3;      // layer-stage 0..2, colgroup 0..3
    const int q = lane >> 4, c = lane & 15;
    const int u  = (g << 4) | c;                // weight row this lane loads
    const int u4 = (g << 4) | (q << 2);         // first hidden unit this lane OWNS
    const long wgbase = (long)blockIdx.x * 64;

    // ---- stage enc (= x(0) = h(-1)) into all layer buffers, parity 1 ----
    if (tid < 512) {
        const int row = tid >> 3, k0 = (tid & 7) << 3;   // 8 floats per thread
        const int j = row >> 4, rr = row & 15;
        const float* p = enc + (wgbase + row) * ESZ + k0;
        floatx4 s0 = *(const floatx4*)p;
        floatx4 s1 = *(const floatx4*)(p + 4);
        half8 v;
        #pragma unroll
        for (int x = 0; x < 4; ++x) { v[x] = (_Float16)s0[x]; v[4 + x] = (_Float16)s1[x]; }
        #pragma unroll
        for (int ly = 0; ly < 3; ++ly)
            *(half8*)&s_hl[((ly * 4 + j) * 2 + 1) * TB16 + rr * LDW + k0] = v;
    }

    // ---- weight fragments (A-operand) ----
    auto ldw8s = [&](const float* p, float sc) {
        floatx4 a = *(const floatx4*)p, b = *(const floatx4*)(p + 4);
        half8 v;
        #pragma unroll
        for (int x = 0; x < 4; ++x) { v[x] = (_Float16)(a[x] * sc); v[4 + x] = (_Float16)(b[x] * sc); }
        return v;
    };
    half8 fR[4], fZ[4], fNi[2], fNh[2], fO[2];
    fO[0] = fO[1] = half8{};
    if (l == 0) {
        // ---- fold W' = W_ih0 @ W_e (fp32), b' = W_ih0 @ b_e ----
        const float* wi = w_ih;
        const float* wh = w_hh;
        floatx4 aR[4], aZ[4], aN[4];
        #pragma unroll
        for (int x = 0; x < 4; ++x) { aR[x] = {0,0,0,0}; aZ[x] = {0,0,0,0}; aN[x] = {0,0,0,0}; }
        float bR = 0.f, bZ = 0.f, bN = 0.f;
        for (int k4 = 0; k4 < 64; k4 += 4) {
            floatx4 wr4 = *(const floatx4*)(wi + (u) * 64 + k4);
            floatx4 wz4 = *(const floatx4*)(wi + (64 + u) * 64 + k4);
            floatx4 wn4 = *(const floatx4*)(wi + (128 + u) * 64 + k4);
            floatx4 be4 = *(const floatx4*)(emb_b + k4);
            #pragma unroll
            for (int kk = 0; kk < 4; ++kk) {
                const float* er = emb_w + (k4 + kk) * 64;
                floatx4 e0 = *(const floatx4*)(er + q * 8);
                floatx4 e1 = *(const floatx4*)(er + q * 8 + 4);
                floatx4 e2 = *(const floatx4*)(er + 32 + q * 8);
                floatx4 e3 = *(const floatx4*)(er + 32 + q * 8 + 4);
                const float wr = wr4[kk], wz = wz4[kk], wn = wn4[kk];
                aR[0] += wr * e0; aR[1] += wr * e1; aR[2] += wr * e2; aR[3] += wr * e3;
                aZ[0] += wz * e0; aZ[1] += wz * e1; aZ[2] += wz * e2; aZ[3] += wz * e3;
                aN[0] += wn * e0; aN[1] += wn * e1; aN[2] += wn * e2; aN[3] += wn * e3;
                bR += wr * be4[kk]; bZ += wz * be4[kk]; bN += wn * be4[kk];
            }
        }
        #pragma unroll
        for (int x = 0; x < 4; ++x) {
            fR[0][x] = (_Float16)(-L2E * aR[0][x]);   fR[0][4 + x] = (_Float16)(-L2E * aR[1][x]);
            fR[1][x] = (_Float16)(-L2E * aR[2][x]);   fR[1][4 + x] = (_Float16)(-L2E * aR[3][x]);
            fZ[0][x] = (_Float16)(-L2E * aZ[0][x]);   fZ[0][4 + x] = (_Float16)(-L2E * aZ[1][x]);
            fZ[1][x] = (_Float16)(-L2E * aZ[2][x]);   fZ[1][4 + x] = (_Float16)(-L2E * aZ[3][x]);
            fNi[0][x] = (_Float16)(2*L2E * aN[0][x]); fNi[0][4 + x] = (_Float16)(2*L2E * aN[1][x]);
            fNi[1][x] = (_Float16)(2*L2E * aN[2][x]); fNi[1][4 + x] = (_Float16)(2*L2E * aN[3][x]);
        }
        fR[2]  = ldw8s(wh + (u) * 64 + q * 8, -L2E);        fR[3]  = ldw8s(wh + (u) * 64 + 32 + q * 8, -L2E);
        fZ[2]  = ldw8s(wh + (64 + u) * 64 + q * 8, -L2E);   fZ[3]  = ldw8s(wh + (64 + u) * 64 + 32 + q * 8, -L2E);
        fNh[0] = ldw8s(wh + (128 + u) * 64 + q * 8, 2*L2E); fNh[1] = ldw8s(wh + (128 + u) * 64 + 32 + q * 8, 2*L2E);
        if (q == 0) {                                // fold-bias per hidden unit u (q-invariant)
            s_btmp[u] = bR; s_btmp[64 + u] = bZ; s_btmp[128 + u] = bN;
        }
        const int oc = (c < NOUTC) ? c : 0;
        fO[0] = ldw8s(out_w + oc * 64 + q * 8, 1.f);
        fO[1] = ldw8s(out_w + oc * 64 + 32 + q * 8, 1.f);
    } else {
        const float* wi = w_ih + l * 3 * HSZ * ESZ;
        const float* wh = w_hh + l * 3 * HSZ * ESZ;
        fR[0]  = ldw8s(wi + (u) * 64 + q * 8, -L2E);        fR[1]  = ldw8s(wi + (u) * 64 + 32 + q * 8, -L2E);
        fR[2]  = ldw8s(wh + (u) * 64 + q * 8, -L2E);        fR[3]  = ldw8s(wh + (u) * 64 + 32 + q * 8, -L2E);
        fZ[0]  = ldw8s(wi + (64 + u) * 64 + q * 8, -L2E);   fZ[1]  = ldw8s(wi + (64 + u) * 64 + 32 + q * 8, -L2E);
        fZ[2]  = ldw8s(wh + (64 + u) * 64 + q * 8, -L2E);   fZ[3]  = ldw8s(wh + (64 + u) * 64 + 32 + q * 8, -L2E);
        fNi[0] = ldw8s(wi + (128 + u) * 64 + q * 8, 2*L2E); fNi[1] = ldw8s(wi + (128 + u) * 64 + 32 + q * 8, 2*L2E);
        fNh[0] = ldw8s(wh + (128 + u) * 64 + q * 8, 2*L2E); fNh[1] = ldw8s(wh + (128 + u) * 64 + 32 + q * 8, 2*L2E);
    }
    __syncthreads();                                 // staging + s_btmp visible

    // ---- per-lane bias vectors (C-init), hidden units u4..u4+3 ----
    floatx4 bR4, bZ4, bNi4, bNh4;
    if (l == 0) {
        #pragma unroll
        for (int i = 0; i < 4; ++i) {
            bR4[i]  = -L2E * (s_btmp[u4 + i] + b_ih[u4 + i] + b_hh[u4 + i]);
            bZ4[i]  = -L2E * (s_btmp[64 + u4 + i] + b_ih[64 + u4 + i] + b_hh[64 + u4 + i]);
            bNi4[i] = 2.f * L2E * (s_btmp[128 + u4 + i] + b_ih[128 + u4 + i]);
            bNh4[i] = 2.f * L2E * b_hh[128 + u4 + i];
        }
    } else {
        const int b0 = l * 192;
        floatx4 bi0 = *(const floatx4*)(b_ih + b0 + u4),       bh0 = *(const floatx4*)(b_hh + b0 + u4);
        floatx4 bi1 = *(const floatx4*)(b_ih + b0 + 64 + u4),  bh1 = *(const floatx4*)(b_hh + b0 + 64 + u4);
        floatx4 bi2 = *(const floatx4*)(b_ih + b0 + 128 + u4), bh2 = *(const floatx4*)(b_hh + b0 + 128 + u4);
        #pragma unroll
        for (int i = 0; i < 4; ++i) {
            bR4[i]  = -L2E * (bi0[i] + bh0[i]);
            bZ4[i]  = -L2E * (bi1[i] + bh1[i]);
            bNi4[i] = 2.f * L2E * bi2[i];
            bNh4[i] = 2.f * L2E * bh2[i];
        }
    }
    const float ob0 = out_b[0], ob1 = out_b[1];

    // ---- fp32 h-carry in VGPRs: ca{j}[i] = h[u4+i][batch row j*16+c] ----
    floatx4 ca0 = *(const floatx4*)(enc + (wgbase +  0 + c) * 64 + u4);
    floatx4 ca1 = *(const floatx4*)(enc + (wgbase + 16 + c) * 64 + u4);
    floatx4 ca2 = *(const floatx4*)(enc + (wgbase + 32 + c) * 64 + u4);
    floatx4 ca3 = *(const floatx4*)(enc + (wgbase + 48 + c) * 64 + u4);

    const int ar = c * LDW + (q << 3);               // act B-frag offset

    // one 16-row GRU cell visit: layer ll, tile j, timestep t.
    // h_ll(t-1) at parity (t&1)^1; writes h_ll(t) at parity t&1.
    auto visit = [&](const int ll, const int j, floatx4& cs, const int t) {
        const int parw = t & 1;
        const _Float16* hb = s_hl + ((ll * 4 + j) * 2 + (parw ^ 1)) * TB16;
        half8 ah0 = *(const half8*)(hb + ar);
        half8 ah1 = *(const half8*)(hb + ar + 32);
        floatx4 accr = bR4, accz = bZ4, accnh = bNh4;
        accr  = MFMA(fR[2], ah0, accr);   accr  = MFMA(fR[3], ah1, accr);
        accz  = MFMA(fZ[2], ah0, accz);   accz  = MFMA(fZ[3], ah1, accz);
        accnh = MFMA(fNh[0], ah0, accnh); accnh = MFMA(fNh[1], ah1, accnh);
        // x: l=0 reads h2(t-1) (parity parw^1); l>=1 reads h_{l-1}(t) (parity parw)
        const _Float16* xb = (ll == 0) ? s_hl + ((8 + j) * 2 + (parw ^ 1)) * TB16
                                       : s_hl + (((ll - 1) * 4 + j) * 2 + parw) * TB16;
        half8 bx0 = *(const half8*)(xb + ar);
        half8 bx1 = *(const half8*)(xb + ar + 32);
        accr = MFMA(fR[0], bx0, accr); accr = MFMA(fR[1], bx1, accr);
        accz = MFMA(fZ[0], bx0, accz); accz = MFMA(fZ[1], bx1, accz);
        floatx4 accni = bNi4;
        accni = MFMA(fNi[0], bx0, accni); accni = MFMA(fNi[1], bx1, accni);
        _Float16* hw = s_hl + ((ll * 4 + j) * 2 + parw) * TB16 + c * LDW + u4;
        half4 hv4; floatx4 hnew;
        #pragma unroll
        for (int i = 0; i < 4; ++i) {
            const float r  = __builtin_amdgcn_rcpf(1.f + __builtin_amdgcn_exp2f(accr[i]));
            const float z  = __builtin_amdgcn_rcpf(1.f + __builtin_amdgcn_exp2f(accz[i]));
            const float a  = accni[i] + r * accnh[i];
            const float n  = 1.f - 2.f * __builtin_amdgcn_rcpf(1.f + __builtin_amdgcn_exp2f(a));
            const float hv = n + z * (cs[i] - n);
            hnew[i] = hv; hv4[i] = (_Float16)hv;
        }
        *(half4*)hw = hv4;
        cs = hnew;
        // out(t-1) = h2(t-1) @ out_w.T + out_b, from L0's x-frags; wave g owns tile g
        if (ll == 0 && g == j && t >= 1) {
            floatx4 oa = {ob0, ob1, 0.f, 0.f};
            oa = MFMA(fO[0], bx0, oa);
            oa = MFMA(fO[1], bx1, oa);
            if (q == 0) {
                const long row = wgbase + j * 16 + c;
                *(floatx2*)(out + (row * TLEN + (t - 1)) * NOUTC) = floatx2{oa[0], oa[1]};
            }
        }
    };

    // ---- systolic stage loop: stage s = 4*s4 + B; layer l works slot s-l ----
    // L0: (t=s4, j=B).  L1: B>=1 -> (s4, B-1), B=0 -> (s4-1, 3).
    // L2: B>=2 -> (s4, B-2), B<2 -> (s4-1, B+2).  516 stages total.
    for (int s4 = 0; s4 < 129; ++s4) {
        // B = 0
        if (l == 0)      { if (s4 < TLEN) visit(0, 0, ca0, s4); }
        else if (l == 1) { if (s4 >= 1)   visit(1, 3, ca3, s4 - 1); }
        else             { if (s4 >= 1)   visit(2, 2, ca2, s4 - 1); }
        __syncthreads();
        // B = 1
        if (l == 0)      { if (s4 < TLEN) visit(0, 1, ca1, s4); }
        else if (l == 1) { if (s4 < TLEN) visit(1, 0, ca0, s4); }
        else             { if (s4 >= 1)   visit(2, 3, ca3, s4 - 1); }
        __syncthreads();
        // B = 2
        if (l == 0)      { if (s4 < TLEN) visit(0, 2, ca2, s4); }
        else if (l == 1) { if (s4 < TLEN) visit(1, 1, ca1, s4); }
        else             { if (s4 < TLEN) visit(2, 0, ca0, s4); }
        __syncthreads();
        // B = 3
        if (l == 0)      { if (s4 < TLEN) visit(0, 3, ca3, s4); }
        else if (l == 1) { if (s4 < TLEN) visit(1, 2, ca2, s4); }
        else             { if (s4 < TLEN) visit(2, 1, ca1, s4); }
        __syncthreads();
    }

    // ---- tail: out(127) from h2(127) (parity 127&1 = 1); L0 wave g -> tile g ----
    if (l == 0) {
        const _Float16* xb = s_hl + ((8 + g) * 2 + 1) * TB16;
        half8 bx0 = *(const half8*)(xb + ar), bx1 = *(const half8*)(xb + ar + 32);
        floatx4 oa = {ob0, ob1, 0.f, 0.f};
        oa = MFMA(fO[0], bx0, oa);
        oa = MFMA(fO[1], bx1, oa);
        if (q == 0) {
            const long row = wgbase + g * 16 + c;
            *(floatx2*)(out + (row * TLEN + 127) * NOUTC) = floatx2{oa[0], oa[1]};
        }
    }
}

extern "C" void kernel_launch(void* const* d_in, const int* in_sizes, int n_in,
                              void* d_out, int out_size, void* d_ws, size_t ws_size,
                              hipStream_t stream) {
    (void)in_sizes; (void)n_in; (void)d_ws; (void)ws_size; (void)out_size;
    const int grid = 16384 / 64;   // 256 workgroups, 1 per CU
    gru_pipe<<<grid, 768, 0, stream>>>(
        (const float*)d_in[0],  // agentFutureTrajEnc
        (const float*)d_in[1],  // emb_w
        (const float*)d_in[2],  // emb_b
        (const float*)d_in[3],  // w_ih
        (const float*)d_in[4],  // w_hh
        (const float*)d_in[5],  // b_ih
        (const float*)d_in[6],  // b_hh
        (const float*)d_in[7],  // out_w
        (const float*)d_in[8],  // out_b
        (float*)d_out);
}

// Round 2
// 453.582 us; speedup vs baseline: 1.0129x; 1.0129x over previous
//
#include <hip/hip_runtime.h>

// FutureTrajDecoder: 3-layer GRU rollout, B=16384, ES=HS=64, T=128, NOUT=2.
// R15 = R14 systolic skeleton minus its structural stalls.
// R14 post-mortem: barrier version == poll version (459 vs 450us) because
// the stage time (~2136 cyc) is dominated by (a) the vmcnt(0) drain hidden
// inside __syncthreads -- every stage exactly one L0 wave does the global
// out-store and then waits ~500 cyc for the store ack before s_barrier,
// stalling all 12 waves, 516 times -- and (b) ~1000 cyc of issue work of
// which 576 is the transcendental floor. LDS pipe is ~10% busy; bank
// conflicts are 2-way (free); polls were never the bottleneck.
// Changes vs R14 (math untouched):
//  1. Raw barrier: s_waitcnt lgkmcnt(0) + s_barrier (asm, memory clobber).
//     LDS handoff ordering preserved; vmcnt NEVER drained in the loop --
//     out-stores are fire-and-forget.
//  2. t-loop unrolled x2: parity is a literal at every visit call site ->
//     all LDS bases constant-fold into ds_read/ds_write offset immediates.
//  3. h-frags and x-frags loaded together at visit top (both barrier-
//     guaranteed) -> one LDS latency exposure per stage, not two.
// Structure: 4 batch tiles x 16 rows; stage s: L0 tile s%4 (t=s/4), L1 one
// tile behind, L2 two behind; barrier between stages; 516 stages. 12 waves
// = 3 layer-stages x 4 colgroups; SIMD g hosts L0/L1/L2 of colgroup g.
// Math: emb folded into L0, gate scales folded into weights, biases in
// MFMA C-init, weights = A operand, fp32 carry in VGPRs, MFMA 16x16x32 f16
// fp32-accum, x-MFMAs chained (R10), out-proj from L0's x-frags.

#define ESZ   64
#define HSZ   64
#define TLEN  128
#define NOUTC 2
#define LDW   72              // fp16 row stride (144 B)
#define TB16  (16*LDW)        // one 16-row activation tile buffer
#define L2E   1.44269504f

typedef _Float16 half8 __attribute__((ext_vector_type(8)));
typedef _Float16 half4 __attribute__((ext_vector_type(4)));
typedef float    floatx4 __attribute__((ext_vector_type(4)));
typedef float    floatx2 __attribute__((ext_vector_type(2)));

#define MFMA(a, b, c) __builtin_amdgcn_mfma_f32_16x16x32_f16((a), (b), (c), 0, 0, 0)

// LDS-ordering barrier WITHOUT vmcnt drain (global stores stay in flight).
#define SBAR() asm volatile("s_waitcnt lgkmcnt(0)\n\ts_barrier" ::: "memory")

__global__ __launch_bounds__(768, 3) void gru_pipe(
    const float* __restrict__ enc,     // (B, 64)
    const float* __restrict__ emb_w,   // (64, 64)
    const float* __restrict__ emb_b,   // (64,)
    const float* __restrict__ w_ih,    // (3, 192, 64)
    const float* __restrict__ w_hh,    // (3, 192, 64)
    const float* __restrict__ b_ih,    // (3, 192)
    const float* __restrict__ b_hh,    // (3, 192)
    const float* __restrict__ out_w,   // (2, 64)
    const float* __restrict__ out_b,   // (2,)
    float* __restrict__ out)           // (B, 128, 2)
{
    __shared__ _Float16 s_hl[3 * 4 * 2 * TB16]; // h_l fp16 [layer][tile][parity]
    __shared__ float    s_btmp[3 * 64];          // folded emb bias (fp32)

    const int tid  = threadIdx.x;
    const int wave = tid >> 6, lane = tid & 63;
    const int l = wave >> 2, g = wave & 3;      // layer-stage 0..2, colgroup 0..3
    const int q = lane >> 4, c = lane & 15;
    const int u  = (g << 4) | c;                // weight row this lane loads
    const int u4 = (g << 4) | (q << 2);         // first hidden unit this lane OWNS
    const long wgbase = (long)blockIdx.x * 64;

    // ---- stage enc (= x(0) = h(-1)) into all layer buffers, parity 1 ----
    if (tid < 512) {
        const int row = tid >> 3, k0 = (tid & 7) << 3;   // 8 floats per thread
        const int j = row >> 4, rr = row & 15;
        const float* p = enc + (wgbase + row) * ESZ + k0;
        floatx4 s0 = *(const floatx4*)p;
        floatx4 s1 = *(const floatx4*)(p + 4);
        half8 v;
        #pragma unroll
        for (int x = 0; x < 4; ++x) { v[x] = (_Float16)s0[x]; v[4 + x] = (_Float16)s1[x]; }
        #pragma unroll
        for (int ly = 0; ly < 3; ++ly)
            *(half8*)&s_hl[((ly * 4 + j) * 2 + 1) * TB16 + rr * LDW + k0] = v;
    }

    // ---- weight fragments (A-operand) ----
    auto ldw8s = [&](const float* p, float sc) {
        floatx4 a = *(const floatx4*)p, b = *(const floatx4*)(p + 4);
        half8 v;
        #pragma unroll
        for (int x = 0; x < 4; ++x) { v[x] = (_Float16)(a[x] * sc); v[4 + x] = (_Float16)(b[x] * sc); }
        return v;
    };
    half8 fR[4], fZ[4], fNi[2], fNh[2], fO[2];
    fO[0] = fO[1] = half8{};
    if (l == 0) {
        // ---- fold W' = W_ih0 @ W_e (fp32), b' = W_ih0 @ b_e ----
        const float* wi = w_ih;
        const float* wh = w_hh;
        floatx4 aR[4], aZ[4], aN[4];
        #pragma unroll
        for (int x = 0; x < 4; ++x) { aR[x] = {0,0,0,0}; aZ[x] = {0,0,0,0}; aN[x] = {0,0,0,0}; }
        float bR = 0.f, bZ = 0.f, bN = 0.f;
        for (int k4 = 0; k4 < 64; k4 += 4) {
            floatx4 wr4 = *(const floatx4*)(wi + (u) * 64 + k4);
            floatx4 wz4 = *(const floatx4*)(wi + (64 + u) * 64 + k4);
            floatx4 wn4 = *(const floatx4*)(wi + (128 + u) * 64 + k4);
            floatx4 be4 = *(const floatx4*)(emb_b + k4);
            #pragma unroll
            for (int kk = 0; kk < 4; ++kk) {
                const float* er = emb_w + (k4 + kk) * 64;
                floatx4 e0 = *(const floatx4*)(er + q * 8);
                floatx4 e1 = *(const floatx4*)(er + q * 8 + 4);
                floatx4 e2 = *(const floatx4*)(er + 32 + q * 8);
                floatx4 e3 = *(const floatx4*)(er + 32 + q * 8 + 4);
                const float wr = wr4[kk], wz = wz4[kk], wn = wn4[kk];
                aR[0] += wr * e0; aR[1] += wr * e1; aR[2] += wr * e2; aR[3] += wr * e3;
                aZ[0] += wz * e0; aZ[1] += wz * e1; aZ[2] += wz * e2; aZ[3] += wz * e3;
                aN[0] += wn * e0; aN[1] += wn * e1; aN[2] += wn * e2; aN[3] += wn * e3;
                bR += wr * be4[kk]; bZ += wz * be4[kk]; bN += wn * be4[kk];
            }
        }
        #pragma unroll
        for (int x = 0; x < 4; ++x) {
            fR[0][x] = (_Float16)(-L2E * aR[0][x]);   fR[0][4 + x] = (_Float16)(-L2E * aR[1][x]);
            fR[1][x] = (_Float16)(-L2E * aR[2][x]);   fR[1][4 + x] = (_Float16)(-L2E * aR[3][x]);
            fZ[0][x] = (_Float16)(-L2E * aZ[0][x]);   fZ[0][4 + x] = (_Float16)(-L2E * aZ[1][x]);
            fZ[1][x] = (_Float16)(-L2E * aZ[2][x]);   fZ[1][4 + x] = (_Float16)(-L2E * aZ[3][x]);
            fNi[0][x] = (_Float16)(2*L2E * aN[0][x]); fNi[0][4 + x] = (_Float16)(2*L2E * aN[1][x]);
            fNi[1][x] = (_Float16)(2*L2E * aN[2][x]); fNi[1][4 + x] = (_Float16)(2*L2E * aN[3][x]);
        }
        fR[2]  = ldw8s(wh + (u) * 64 + q * 8, -L2E);        fR[3]  = ldw8s(wh + (u) * 64 + 32 + q * 8, -L2E);
        fZ[2]  = ldw8s(wh + (64 + u) * 64 + q * 8, -L2E);   fZ[3]  = ldw8s(wh + (64 + u) * 64 + 32 + q * 8, -L2E);
        fNh[0] = ldw8s(wh + (128 + u) * 64 + q * 8, 2*L2E); fNh[1] = ldw8s(wh + (128 + u) * 64 + 32 + q * 8, 2*L2E);
        if (q == 0) {                                // fold-bias per hidden unit u (q-invariant)
            s_btmp[u] = bR; s_btmp[64 + u] = bZ; s_btmp[128 + u] = bN;
        }
        const int oc = (c < NOUTC) ? c : 0;
        fO[0] = ldw8s(out_w + oc * 64 + q * 8, 1.f);
        fO[1] = ldw8s(out_w + oc * 64 + 32 + q * 8, 1.f);
    } else {
        const float* wi = w_ih + l * 3 * HSZ * ESZ;
        const float* wh = w_hh + l * 3 * HSZ * ESZ;
        fR[0]  = ldw8s(wi + (u) * 64 + q * 8, -L2E);        fR[1]  = ldw8s(wi + (u) * 64 + 32 + q * 8, -L2E);
        fR[2]  = ldw8s(wh + (u) * 64 + q * 8, -L2E);        fR[3]  = ldw8s(wh + (u) * 64 + 32 + q * 8, -L2E);
        fZ[0]  = ldw8s(wi + (64 + u) * 64 + q * 8, -L2E);   fZ[1]  = ldw8s(wi + (64 + u) * 64 + 32 + q * 8, -L2E);
        fZ[2]  = ldw8s(wh + (64 + u) * 64 + q * 8, -L2E);   fZ[3]  = ldw8s(wh + (64 + u) * 64 + 32 + q * 8, -L2E);
        fNi[0] = ldw8s(wi + (128 + u) * 64 + q * 8, 2*L2E); fNi[1] = ldw8s(wi + (128 + u) * 64 + 32 + q * 8, 2*L2E);
        fNh[0] = ldw8s(wh + (128 + u) * 64 + q * 8, 2*L2E); fNh[1] = ldw8s(wh + (128 + u) * 64 + 32 + q * 8, 2*L2E);
    }
    __syncthreads();                                 // staging + s_btmp visible (once; full sync ok)

    // ---- per-lane bias vectors (C-init), hidden units u4..u4+3 ----
    floatx4 bR4, bZ4, bNi4, bNh4;
    if (l == 0) {
        #pragma unroll
        for (int i = 0; i < 4; ++i) {
            bR4[i]  = -L2E * (s_btmp[u4 + i] + b_ih[u4 + i] + b_hh[u4 + i]);
            bZ4[i]  = -L2E * (s_btmp[64 + u4 + i] + b_ih[64 + u4 + i] + b_hh[64 + u4 + i]);
            bNi4[i] = 2.f * L2E * (s_btmp[128 + u4 + i] + b_ih[128 + u4 + i]);
            bNh4[i] = 2.f * L2E * b_hh[128 + u4 + i];
        }
    } else {
        const int b0 = l * 192;
        floatx4 bi0 = *(const floatx4*)(b_ih + b0 + u4),       bh0 = *(const floatx4*)(b_hh + b0 + u4);
        floatx4 bi1 = *(const floatx4*)(b_ih + b0 + 64 + u4),  bh1 = *(const floatx4*)(b_hh + b0 + 64 + u4);
        floatx4 bi2 = *(const floatx4*)(b_ih + b0 + 128 + u4), bh2 = *(const floatx4*)(b_hh + b0 + 128 + u4);
        #pragma unroll
        for (int i = 0; i < 4; ++i) {
            bR4[i]  = -L2E * (bi0[i] + bh0[i]);
            bZ4[i]  = -L2E * (bi1[i] + bh1[i]);
            bNi4[i] = 2.f * L2E * bi2[i];
            bNh4[i] = 2.f * L2E * bh2[i];
        }
    }
    const float ob0 = out_b[0], ob1 = out_b[1];

    // ---- fp32 h-carry in VGPRs: ca{j}[i] = h[u4+i][batch row j*16+c] ----
    floatx4 ca0 = *(const floatx4*)(enc + (wgbase +  0 + c) * 64 + u4);
    floatx4 ca1 = *(const floatx4*)(enc + (wgbase + 16 + c) * 64 + u4);
    floatx4 ca2 = *(const floatx4*)(enc + (wgbase + 32 + c) * 64 + u4);
    floatx4 ca3 = *(const floatx4*)(enc + (wgbase + 48 + c) * 64 + u4);

    const int ar = c * LDW + (q << 3);               // act B-frag offset

    // one 16-row GRU cell visit: layer ll, tile j, timestep t, parity parw
    // (parw == t&1, passed as a LITERAL so all LDS bases constant-fold).
    auto visit = [&](const int ll, const int j, floatx4& cs, const int t,
                     const int parw) {
        const _Float16* hb = s_hl + ((ll * 4 + j) * 2 + (parw ^ 1)) * TB16;
        const _Float16* xb = (ll == 0) ? s_hl + ((8 + j) * 2 + (parw ^ 1)) * TB16
                                       : s_hl + (((ll - 1) * 4 + j) * 2 + parw) * TB16;
        // both operands are barrier-guaranteed: load together, one latency exposure
        half8 ah0 = *(const half8*)(hb + ar);
        half8 ah1 = *(const half8*)(hb + ar + 32);
        half8 bx0 = *(const half8*)(xb + ar);
        half8 bx1 = *(const half8*)(xb + ar + 32);
        floatx4 accr = bR4, accz = bZ4, accnh = bNh4;
        accr  = MFMA(fR[2], ah0, accr);   accr  = MFMA(fR[3], ah1, accr);
        accz  = MFMA(fZ[2], ah0, accz);   accz  = MFMA(fZ[3], ah1, accz);
        accnh = MFMA(fNh[0], ah0, accnh); accnh = MFMA(fNh[1], ah1, accnh);
        accr = MFMA(fR[0], bx0, accr); accr = MFMA(fR[1], bx1, accr);
        accz = MFMA(fZ[0], bx0, accz); accz = MFMA(fZ[1], bx1, accz);
        floatx4 accni = bNi4;
        accni = MFMA(fNi[0], bx0, accni); accni = MFMA(fNi[1], bx1, accni);
        _Float16* hw = s_hl + ((ll * 4 + j) * 2 + parw) * TB16 + c * LDW + u4;
        half4 hv4; floatx4 hnew;
        #pragma unroll
        for (int i = 0; i < 4; ++i) {
            const float r  = __builtin_amdgcn_rcpf(1.f + __builtin_amdgcn_exp2f(accr[i]));
            const float z  = __builtin_amdgcn_rcpf(1.f + __builtin_amdgcn_exp2f(accz[i]));
            const float a  = accni[i] + r * accnh[i];
            const float n  = 1.f - 2.f * __builtin_amdgcn_rcpf(1.f + __builtin_amdgcn_exp2f(a));
            const float hv = n + z * (cs[i] - n);
            hnew[i] = hv; hv4[i] = (_Float16)hv;
        }
        *(half4*)hw = hv4;
        cs = hnew;
        // out(t-1) = h2(t-1) @ out_w.T + out_b, from L0's x-frags; wave g owns tile g
        if (ll == 0 && g == j && t >= 1) {
            floatx4 oa = {ob0, ob1, 0.f, 0.f};
            oa = MFMA(fO[0], bx0, oa);
            oa = MFMA(fO[1], bx1, oa);
            if (q == 0) {
                const long row = wgbase + j * 16 + c;
                *(floatx2*)(out + (row * TLEN + (t - 1)) * NOUTC) = floatx2{oa[0], oa[1]};
            }
        }
    };

    // ---- systolic stage loop, x2 unrolled so parities are literals ----
    // stage s = 4*s4 + B; L0 does (t=s4, j=B); L1 one tile behind; L2 two.
    for (int s4 = 0; s4 < TLEN; s4 += 2) {
        // ==== even t = s4 (parw 0); lagging t = s4-1 (parw 1) ====
        if (l == 0)      visit(0, 0, ca0, s4, 0);
        else if (l == 1) { if (s4) visit(1, 3, ca3, s4 - 1, 1); }
        else             { if (s4) visit(2, 2, ca2, s4 - 1, 1); }
        SBAR();
        if (l == 0)      visit(0, 1, ca1, s4, 0);
        else if (l == 1) visit(1, 0, ca0, s4, 0);
        else             { if (s4) visit(2, 3, ca3, s4 - 1, 1); }
        SBAR();
        if (l == 0)      visit(0, 2, ca2, s4, 0);
        else if (l == 1) visit(1, 1, ca1, s4, 0);
        else             visit(2, 0, ca0, s4, 0);
        SBAR();
        if (l == 0)      visit(0, 3, ca3, s4, 0);
        else if (l == 1) visit(1, 2, ca2, s4, 0);
        else             visit(2, 1, ca1, s4, 0);
        SBAR();
        // ==== odd t = s4+1 (parw 1); lagging t = s4 (parw 0) ====
        if (l == 0)      visit(0, 0, ca0, s4 + 1, 1);
        else if (l == 1) visit(1, 3, ca3, s4, 0);
        else             visit(2, 2, ca2, s4, 0);
        SBAR();
        if (l == 0)      visit(0, 1, ca1, s4 + 1, 1);
        else if (l == 1) visit(1, 0, ca0, s4 + 1, 1);
        else             visit(2, 3, ca3, s4, 0);
        SBAR();
        if (l == 0)      visit(0, 2, ca2, s4 + 1, 1);
        else if (l == 1) visit(1, 1, ca1, s4 + 1, 1);
        else             visit(2, 0, ca0, s4 + 1, 1);
        SBAR();
        if (l == 0)      visit(0, 3, ca3, s4 + 1, 1);
        else if (l == 1) visit(1, 2, ca2, s4 + 1, 1);
        else             visit(2, 1, ca1, s4 + 1, 1);
        SBAR();
    }
    // ==== epilogue (s4 = 128): finish lagging t = 127 (parw 1) ====
    if (l == 1)      visit(1, 3, ca3, TLEN - 1, 1);
    else if (l == 2) visit(2, 2, ca2, TLEN - 1, 1);
    SBAR();
    if (l == 2)      visit(2, 3, ca3, TLEN - 1, 1);
    SBAR();

    // ---- tail: out(127) from h2(127) (parity 1); L0 wave g -> tile g ----
    if (l == 0) {
        const _Float16* xb = s_hl + ((8 + g) * 2 + 1) * TB16;
        half8 bx0 = *(const half8*)(xb + ar), bx1 = *(const half8*)(xb + ar + 32);
        floatx4 oa = {ob0, ob1, 0.f, 0.f};
        oa = MFMA(fO[0], bx0, oa);
        oa = MFMA(fO[1], bx1, oa);
        if (q == 0) {
            const long row = wgbase + g * 16 + c;
            *(floatx2*)(out + (row * TLEN + 127) * NOUTC) = floatx2{oa[0], oa[1]};
        }
    }
}

extern "C" void kernel_launch(void* const* d_in, const int* in_sizes, int n_in,
                              void* d_out, int out_size, void* d_ws, size_t ws_size,
                              hipStream_t stream) {
    (void)in_sizes; (void)n_in; (void)d_ws; (void)ws_size; (void)out_size;
    const int grid = 16384 / 64;   // 256 workgroups, 1 per CU
    gru_pipe<<<grid, 768, 0, stream>>>(
        (const float*)d_in[0],  // agentFutureTrajEnc
        (const float*)d_in[1],  // emb_w
        (const float*)d_in[2],  // emb_b
        (const float*)d_in[3],  // w_ih
        (const float*)d_in[4],  // w_hh
        (const float*)d_in[5],  // b_ih
        (const float*)d_in[6],  // b_hh
        (const float*)d_in[7],  // out_w
        (const float*)d_in[8],  // out_b
        (float*)d_out);
}